// Round 3
// baseline (5628.371 us; speedup 1.0000x reference)
//
#include <hip/hip_runtime.h>
#include <stdint.h>

#define B_   64
#define T_   512
#define EI_  1024
#define EO_  1024

typedef __attribute__((ext_vector_type(4))) float  f32x4;
typedef __attribute__((ext_vector_type(8))) short  s16x8;
typedef __attribute__((ext_vector_type(4))) unsigned short u16x4;

__device__ __forceinline__ unsigned short f2bf(float f) {
    union { float f; unsigned int u; } v; v.f = f;
    unsigned int r = v.u + 0x7FFFu + ((v.u >> 16) & 1u);
    return (unsigned short)(r >> 16);
}

// ---- prep: LDS tile-transpose both weight matrices to bf16 [N][K]; init hbf parity-1; zero flags ----
__global__ void prep_kernel(const float* __restrict__ wxh, const float* __restrict__ whf,
                            const float* __restrict__ h0,
                            unsigned short* __restrict__ wxhT, unsigned short* __restrict__ whfT,
                            unsigned short* __restrict__ hbf1, unsigned int* __restrict__ flags)
{
    __shared__ unsigned short Ts[64][72];
    const int bid = blockIdx.x;
    const float* src = (bid & 1) ? whf : wxh;
    unsigned short* dst = (bid & 1) ? whfT : wxhT;
    const int tile = bid >> 1;                  // 0..255
    const int k0 = (tile >> 4) * 64, n0 = (tile & 15) * 64;
    const int tid = threadIdx.x;

    #pragma unroll
    for (int it = 0; it < 4; ++it) {            // read 64x64 f32, coalesced rows
        int r  = it * 16 + (tid >> 4);
        int cq = tid & 15;
        f32x4 v = *(const f32x4*)(src + (size_t)(k0 + r) * EO_ + n0 + cq * 4);
        #pragma unroll
        for (int i = 0; i < 4; ++i) Ts[cq * 4 + i][r] = f2bf(v[i]);
    }
    __syncthreads();
    #pragma unroll
    for (int it = 0; it < 2; ++it) {            // write transposed, coalesced 16B rows
        int n = it * 32 + (tid >> 3);
        int c = tid & 7;
        s16x8 v = *(const s16x8*)(&Ts[n][c * 8]);
        *(s16x8*)(dst + (size_t)(n0 + n) * EI_ + k0 + c * 8) = v;
    }
    if (bid < 256) {                            // h0 -> bf16 parity-1 buffer
        int j = bid * 256 + tid;
        hbf1[j] = f2bf(h0[j]);
    }
    if (bid == 0) flags[tid] = 0u;              // 256 per-wave flags
}

// ---- kernel 1: G = tanh(X @ wxh) into the outs region of d_out (unchanged, proven) ----
__launch_bounds__(256, 2)
__global__ void gemm_g_kernel(const float* __restrict__ X,
                              const unsigned short* __restrict__ WT,
                              float* __restrict__ out)
{
    __shared__ alignas(16) unsigned short As[128 * 72];
    __shared__ alignas(16) unsigned short Bs[128 * 72];

    const int bid = blockIdx.x;
    const int bn = bid & 7, bm = bid >> 3;
    const int m0 = bm * 128, n0 = bn * 128;
    const int tid  = threadIdx.x;
    const int lane = tid & 63, w = tid >> 6;
    const int wr = w >> 1, wc = w & 1;
    const int l15 = lane & 15, lg = lane >> 4;

    f32x4 acc[4][4] = {};

    for (int kt = 0; kt < EI_ / 64; ++kt) {
        const int k0 = kt * 64;
        #pragma unroll
        for (int p = 0; p < 8; ++p) {
            int row = p * 16 + (tid >> 4);
            int kq  = tid & 15;
            f32x4 v = *(const f32x4*)(X + (size_t)(m0 + row) * EI_ + k0 + kq * 4);
            u16x4 hv;
            hv[0] = f2bf(v[0]); hv[1] = f2bf(v[1]); hv[2] = f2bf(v[2]); hv[3] = f2bf(v[3]);
            *(u16x4*)(&As[row * 72 + kq * 4]) = hv;
        }
        #pragma unroll
        for (int p = 0; p < 4; ++p) {
            int n  = p * 32 + (tid >> 3);
            int kq = tid & 7;
            s16x8 v = *(const s16x8*)(WT + (size_t)(n0 + n) * EI_ + k0 + kq * 8);
            *(s16x8*)(&Bs[n * 72 + kq * 8]) = v;
        }
        __syncthreads();
        #pragma unroll
        for (int kk = 0; kk < 2; ++kk) {
            s16x8 a[4], b[4];
            #pragma unroll
            for (int mt = 0; mt < 4; ++mt)
                a[mt] = *(const s16x8*)(&As[(wr * 64 + mt * 16 + l15) * 72 + kk * 32 + lg * 8]);
            #pragma unroll
            for (int nt = 0; nt < 4; ++nt)
                b[nt] = *(const s16x8*)(&Bs[(wc * 64 + nt * 16 + l15) * 72 + kk * 32 + lg * 8]);
            #pragma unroll
            for (int mt = 0; mt < 4; ++mt)
                #pragma unroll
                for (int nt = 0; nt < 4; ++nt)
                    acc[mt][nt] = __builtin_amdgcn_mfma_f32_16x16x32_bf16(a[mt], b[nt], acc[mt][nt], 0, 0, 0);
        }
        __syncthreads();
    }
    #pragma unroll
    for (int mt = 0; mt < 4; ++mt) {
        #pragma unroll
        for (int nt = 0; nt < 4; ++nt) {
            #pragma unroll
            for (int r = 0; r < 4; ++r) {
                int row = wr * 64 + mt * 16 + lg * 4 + r;
                int col = wc * 64 + nt * 16 + l15;
                float s = acc[mt][nt][r];
                float e = __expf(2.f * s);
                out[(size_t)(m0 + row) * EO_ + n0 + col] = 1.f - 2.f / (e + 1.f);
            }
        }
    }
}

// ---- kernel 2: recurrence, fully wave-autonomous. 64 blocks x 256 thr = 256 waves.
// Wave = 16 cols x 16 rows, full K=1024: whf slice in 128 VGPRs, NO LDS, NO barriers.
// Cross-wave H + per-wave flags via agent-scope relaxed atomics (L3-coherent).
__launch_bounds__(256, 1)
__global__ void recur_kernel(const float* __restrict__ h0,
                             const unsigned short* __restrict__ whfT, // whf^T bf16 [N][K]
                             unsigned short* hbf,                     // [2][B_*EO_]
                             unsigned int* flags,                     // [4][64] per-wave
                             float* out)
{
    const int bid = blockIdx.x;          // 0..63
    const int g = bid >> 4;              // batch group 0..3
    const int q = bid & 15;              // col block 0..15
    const int tid = threadIdx.x;
    const int lane = tid & 63, w = tid >> 6;       // 4 waves/block
    const int l15 = lane & 15, lg = lane >> 4;
    const int wid = q * 4 + w;                     // wave id within group, 0..63
    const int col = wid * 16 + l15;                // output column 0..1023
    const int rowbase = g * 16 + lg * 4;           // this lane's 4 batch rows

    // whf columns resident in registers: 32 k-slots x 8 bf16 = 128 VGPR
    s16x8 Wf[32];
    #pragma unroll
    for (int kk = 0; kk < 32; ++kk)
        Wf[kk] = *(const s16x8*)(whfT + (size_t)col * EO_ + kk * 32 + lg * 8);

    float h[4];
    #pragma unroll
    for (int r = 0; r < 4; ++r)
        h[r] = h0[(size_t)(rowbase + r) * EO_ + col];

    unsigned int* const flg = flags + g * 64;

    for (int t = 0; t < T_; ++t) {
        // prefetch g_t (no peer dependence) before the poll
        float gv[4];
        #pragma unroll
        for (int r = 0; r < 4; ++r)
            gv[r] = out[((size_t)(rowbase + r) * T_ + t) * EO_ + col];

        if (t > 0) {
            const unsigned int want = (unsigned int)t;
            int spins = 0;
            for (;;) {
                unsigned int f = __hip_atomic_load(&flg[lane], __ATOMIC_RELAXED,
                                                   __HIP_MEMORY_SCOPE_AGENT);
                if (__ballot(f >= want) == ~0ULL) break;
                if (++spins > (1 << 20)) break;    // safety valve
            }
        }
        asm volatile("" ::: "memory");

        // issue ALL 64 coherent A-loads back-to-back (one L3 latency)
        const unsigned short* arow = hbf + (size_t)((t & 1) ^ 1) * (B_ * EO_)
                                   + (size_t)(g * 16 + l15) * EO_ + lg * 8;
        unsigned long long abuf[64];
        #pragma unroll
        for (int kk = 0; kk < 32; ++kk) {
            abuf[2 * kk]     = __hip_atomic_load((const unsigned long long*)(arow + kk * 32),
                                                 __ATOMIC_RELAXED, __HIP_MEMORY_SCOPE_AGENT);
            abuf[2 * kk + 1] = __hip_atomic_load((const unsigned long long*)(arow + kk * 32 + 4),
                                                 __ATOMIC_RELAXED, __HIP_MEMORY_SCOPE_AGENT);
        }
        f32x4 acc[4] = {};
        #pragma unroll
        for (int kk = 0; kk < 32; ++kk) {
            union { unsigned long long u[2]; s16x8 v; } av;
            av.u[0] = abuf[2 * kk]; av.u[1] = abuf[2 * kk + 1];
            acc[kk & 3] = __builtin_amdgcn_mfma_f32_16x16x32_bf16(av.v, Wf[kk], acc[kk & 3], 0, 0, 0);
        }

        unsigned short hb[4];
        #pragma unroll
        for (int r = 0; r < 4; ++r) {
            float s = acc[0][r] + acc[1][r] + acc[2][r] + acc[3][r];
            float fg = 1.f / (1.f + __expf(-s));
            h[r] = (1.f - fg) * h[r] + fg * gv[r];
            out[((size_t)(rowbase + r) * T_ + t) * EO_ + col] = h[r];
            hb[r] = f2bf(h[r]);
        }
        // packed u32 coherent H store (even lanes store self | neighbor<<16)
        unsigned short* hw = hbf + (size_t)(t & 1) * (B_ * EO_);
        #pragma unroll
        for (int r = 0; r < 4; ++r) {
            unsigned int other = (unsigned int)__shfl_xor((int)(unsigned int)hb[r], 1);
            if (!(lane & 1)) {
                unsigned int packed = (unsigned int)hb[r] | (other << 16);
                __hip_atomic_store((unsigned int*)(hw + (size_t)(rowbase + r) * EO_ + col),
                                   packed, __ATOMIC_RELAXED, __HIP_MEMORY_SCOPE_AGENT);
            }
        }
        // wave-local drain: all prior stores complete before releasing our flag
        asm volatile("s_waitcnt vmcnt(0)" ::: "memory");
        if (lane == 0)
            __hip_atomic_store(&flg[wid], (unsigned int)(t + 1),
                               __ATOMIC_RELAXED, __HIP_MEMORY_SCOPE_AGENT);
    }
    #pragma unroll
    for (int r = 0; r < 4; ++r)
        out[(size_t)B_ * T_ * EO_ + (size_t)(rowbase + r) * EO_ + col] = h[r];
}

extern "C" void kernel_launch(void* const* d_in, const int* in_sizes, int n_in,
                              void* d_out, int out_size, void* d_ws, size_t ws_size,
                              hipStream_t stream)
{
    const float* x   = (const float*)d_in[0];
    const float* h0  = (const float*)d_in[1];
    const float* wxh = (const float*)d_in[2];
    const float* whf = (const float*)d_in[3];
    float* out = (float*)d_out;

    char* ws = (char*)d_ws;
    unsigned short* whfT  = (unsigned short*)(ws);
    unsigned short* wxhT  = (unsigned short*)(ws + (size_t)2 * 1024 * 1024);
    unsigned short* hbf   = (unsigned short*)(ws + (size_t)4 * 1024 * 1024);
    unsigned int*   flags = (unsigned int*)  (ws + (size_t)4 * 1024 * 1024 + 512 * 1024);

    prep_kernel<<<512, 256, 0, stream>>>(wxh, whf, h0, wxhT, whfT, hbf + B_ * EO_, flags);
    gemm_g_kernel<<<2048, 256, 0, stream>>>(x, wxhT, out);
    recur_kernel<<<64, 256, 0, stream>>>(h0, whfT, hbf, flags, out);
}